// Round 1
// baseline (237.559 us; speedup 1.0000x reference)
//
#include <hip/hip_runtime.h>
#include <hip/hip_bf16.h>

#define N_ROWS 1024
#define DIM 256
#define HID 512

// ---------------- zero small ws region ----------------
__global__ void zero_kernel(float* p, int n) {
    int i = blockIdx.x * blockDim.x + threadIdx.x;
    if (i < n) p[i] = 0.0f;
}

// ---------------- column stats of domain_b ----------------
// ebsum[d] = sum_j b[j,d] ; eb2sum[d] = sum_j b[j,d]^2
__global__ __launch_bounds__(256) void colstats_kernel(const float* __restrict__ B,
                                                       float* __restrict__ ebsum,
                                                       float* __restrict__ eb2sum) {
    int d = threadIdx.x;            // 256 columns
    int r0 = blockIdx.x * 64;       // 16 blocks x 64 rows
    float s = 0.f, s2 = 0.f;
    #pragma unroll 4
    for (int r = 0; r < 64; ++r) {
        float v = B[(r0 + r) * DIM + d];
        s += v; s2 += v * v;
    }
    atomicAdd(&ebsum[d], s);
    atomicAdd(&eb2sum[d], s2);
}

// ---------------- fp32 tiled GEMM: C = act(A @ W + bias) ----------------
// A: M x K row-major, W: K x Nout row-major, C: M x Nout
// ACT: 0 = none, 1 = relu
template <int ACT>
__global__ __launch_bounds__(256) void gemm_bias(const float* __restrict__ A,
                                                 const float* __restrict__ W,
                                                 const float* __restrict__ bias,
                                                 float* __restrict__ C,
                                                 int M, int K, int Nout) {
    __shared__ float As[16][64 + 1];  // [k][m]
    __shared__ float Bs[16][64 + 1];  // [k][n]
    const int tid = threadIdx.x;
    const int bm = blockIdx.y * 64, bn = blockIdx.x * 64;
    const int tx = tid & 15, ty = tid >> 4;
    float acc[4][4] = {};

    for (int k0 = 0; k0 < K; k0 += 16) {
        #pragma unroll
        for (int t = 0; t < 4; ++t) {
            int pos = tid + t * 256;          // 64x16 A tile
            int m = pos >> 4, kk = pos & 15;
            As[kk][m] = A[(bm + m) * K + k0 + kk];
        }
        #pragma unroll
        for (int t = 0; t < 4; ++t) {
            int pos = tid + t * 256;          // 16x64 W tile
            int kk = pos >> 6, n = pos & 63;
            Bs[kk][n] = W[(k0 + kk) * Nout + bn + n];
        }
        __syncthreads();
        #pragma unroll
        for (int kk = 0; kk < 16; ++kk) {
            float a[4], b[4];
            #pragma unroll
            for (int r = 0; r < 4; ++r) a[r] = As[kk][ty * 4 + r];
            #pragma unroll
            for (int c = 0; c < 4; ++c) b[c] = Bs[kk][tx * 4 + c];
            #pragma unroll
            for (int r = 0; r < 4; ++r)
                #pragma unroll
                for (int c = 0; c < 4; ++c)
                    acc[r][c] = fmaf(a[r], b[c], acc[r][c]);
        }
        __syncthreads();
    }

    #pragma unroll
    for (int r = 0; r < 4; ++r) {
        int m = bm + ty * 4 + r;
        #pragma unroll
        for (int c = 0; c < 4; ++c) {
            int n = bn + tx * 4 + c;
            float v = acc[r][c] + bias[n];
            if (ACT == 1) v = fmaxf(v, 0.f);
            C[m * Nout + n] = v;
        }
    }
}

// ---------------- fused epilogue + loss reduction ----------------
// loss contribution of row i: sum_d [ (Eb2 - 2*mu*Eb + mu^2) * exp(-lv) + lv ]
// with mu = l2norm(mu_raw[i,:]), lv = tanh(lv_raw[i,:])
__global__ __launch_bounds__(256) void loss_kernel(const float* __restrict__ mu_raw,
                                                   const float* __restrict__ lv_raw,
                                                   const float* __restrict__ ebsum,
                                                   const float* __restrict__ eb2sum,
                                                   float* __restrict__ acc) {
    const int wave = threadIdx.x >> 6;
    const int lane = threadIdx.x & 63;
    const int i = blockIdx.x * 4 + wave;      // 256 blocks x 4 waves = 1024 rows
    const float invN = 1.0f / (float)N_ROWS;

    float m4[4], l4[4];
    float ss = 0.f;
    #pragma unroll
    for (int t = 0; t < 4; ++t) {
        int d = lane + t * 64;
        m4[t] = mu_raw[i * DIM + d];
        l4[t] = lv_raw[i * DIM + d];
        ss = fmaf(m4[t], m4[t], ss);
    }
    #pragma unroll
    for (int o = 32; o > 0; o >>= 1) ss += __shfl_xor(ss, o, 64);
    const float inv_norm = 1.f / fmaxf(sqrtf(ss), 1e-12f);

    float tsum = 0.f;
    #pragma unroll
    for (int t = 0; t < 4; ++t) {
        int d = lane + t * 64;
        float mu = m4[t] * inv_norm;
        float lv = tanhf(l4[t]);
        float iv = expf(-lv);
        float eb = ebsum[d] * invN;
        float eb2 = eb2sum[d] * invN;
        float diff2 = fmaf(mu, mu, fmaf(-2.f * mu, eb, eb2));
        tsum += fmaf(diff2, iv, lv);
    }
    #pragma unroll
    for (int o = 32; o > 0; o >>= 1) tsum += __shfl_xor(tsum, o, 64);
    if (lane == 0) atomicAdd(acc, tsum);
}

__global__ void finalize_kernel(const float* __restrict__ acc, float* __restrict__ out) {
    out[0] = acc[0] * (1.0f / (float)N_ROWS);
}

extern "C" void kernel_launch(void* const* d_in, const int* in_sizes, int n_in,
                              void* d_out, int out_size, void* d_ws, size_t ws_size,
                              hipStream_t stream) {
    const float* domain_a = (const float*)d_in[0];
    const float* domain_b = (const float*)d_in[1];
    const float* mu_w0 = (const float*)d_in[2];
    const float* mu_b0 = (const float*)d_in[3];
    const float* mu_w1 = (const float*)d_in[4];
    const float* mu_b1 = (const float*)d_in[5];
    const float* mu_w2 = (const float*)d_in[6];
    const float* mu_b2 = (const float*)d_in[7];
    const float* lv_w0 = (const float*)d_in[8];
    const float* lv_b0 = (const float*)d_in[9];
    const float* lv_w1 = (const float*)d_in[10];
    const float* lv_b1 = (const float*)d_in[11];
    const float* lv_w2 = (const float*)d_in[12];
    const float* lv_b2 = (const float*)d_in[13];

    float* ws = (float*)d_ws;
    // workspace layout (floats)
    float* ebsum  = ws + 0;        // 256
    float* eb2sum = ws + 256;      // 256
    float* acc    = ws + 512;      // 1
    float* h1_mu  = ws + 1024;                 // 1024*512
    float* h2_mu  = h1_mu + N_ROWS * HID;      // 1024*512
    float* mu_raw = h2_mu + N_ROWS * HID;      // 1024*256
    float* h1_lv  = mu_raw + N_ROWS * DIM;
    float* h2_lv  = h1_lv + N_ROWS * HID;
    float* lv_raw = h2_lv + N_ROWS * HID;

    zero_kernel<<<3, 256, 0, stream>>>(ws, 513);
    colstats_kernel<<<16, 256, 0, stream>>>(domain_b, ebsum, eb2sum);

    // mu net
    gemm_bias<1><<<dim3(HID / 64, N_ROWS / 64), 256, 0, stream>>>(domain_a, mu_w0, mu_b0, h1_mu, N_ROWS, DIM, HID);
    gemm_bias<1><<<dim3(HID / 64, N_ROWS / 64), 256, 0, stream>>>(h1_mu, mu_w1, mu_b1, h2_mu, N_ROWS, HID, HID);
    gemm_bias<0><<<dim3(DIM / 64, N_ROWS / 64), 256, 0, stream>>>(h2_mu, mu_w2, mu_b2, mu_raw, N_ROWS, HID, DIM);
    // lv net
    gemm_bias<1><<<dim3(HID / 64, N_ROWS / 64), 256, 0, stream>>>(domain_a, lv_w0, lv_b0, h1_lv, N_ROWS, DIM, HID);
    gemm_bias<1><<<dim3(HID / 64, N_ROWS / 64), 256, 0, stream>>>(h1_lv, lv_w1, lv_b1, h2_lv, N_ROWS, HID, HID);
    gemm_bias<0><<<dim3(DIM / 64, N_ROWS / 64), 256, 0, stream>>>(h2_lv, lv_w2, lv_b2, lv_raw, N_ROWS, HID, DIM);

    loss_kernel<<<N_ROWS / 4, 256, 0, stream>>>(mu_raw, lv_raw, ebsum, eb2sum, acc);
    finalize_kernel<<<1, 1, 0, stream>>>(acc, d_out ? (float*)d_out : nullptr);
}

// Round 2
// 77.315 us; speedup vs baseline: 3.0726x; 3.0726x over previous
//
#include <hip/hip_runtime.h>
#include <hip/hip_bf16.h>

#define N_ROWS 1024
#define DIM 256
#define HID 512

// ---------------- zero small ws region ----------------
__global__ void zero_kernel(float* p, int n) {
    int i = blockIdx.x * blockDim.x + threadIdx.x;
    if (i < n) p[i] = 0.0f;
}

// ---------------- column stats of domain_b ----------------
__global__ __launch_bounds__(256) void colstats_kernel(const float* __restrict__ B,
                                                       float* __restrict__ ebsum,
                                                       float* __restrict__ eb2sum) {
    int d = threadIdx.x;            // 256 columns
    int r0 = blockIdx.x * 16;       // 64 blocks x 16 rows
    float s = 0.f, s2 = 0.f;
    #pragma unroll
    for (int r = 0; r < 16; ++r) {
        float v = B[(r0 + r) * DIM + d];
        s += v; s2 += v * v;
    }
    atomicAdd(&ebsum[d], s);
    atomicAdd(&eb2sum[d], s2);
}

// ---------------- fp32 GEMM, 32x64 tile, double-buffered, both nets ----------------
// A: M x K row-major, W: K x Nout row-major, C = act(A@W + bias): M x Nout
// 256 threads, each computes 2 rows x 4 cols. BK = 32.
template <int ACT>
__global__ __launch_bounds__(256) void gemm2(const float* __restrict__ A0, const float* __restrict__ A1,
                                             const float* __restrict__ W0, const float* __restrict__ W1,
                                             const float* __restrict__ bias0, const float* __restrict__ bias1,
                                             float* __restrict__ C0, float* __restrict__ C1,
                                             int M, int K, int Nout) {
    const int net = blockIdx.z;
    const float* __restrict__ A = net ? A1 : A0;
    const float* __restrict__ W = net ? W1 : W0;
    const float* __restrict__ bias = net ? bias1 : bias0;
    float* __restrict__ C = net ? C1 : C0;

    __shared__ float As[2][32][36];   // [buf][m][k]  pad 36 floats
    __shared__ float Bs[2][32][72];   // [buf][k][n]  pad 72 floats

    const int tid = threadIdx.x;
    const int bm = blockIdx.y * 32, bn = blockIdx.x * 64;
    const int tx = tid & 15;          // col group: 4 cols at tx*4
    const int ty = tid >> 4;          // row group: 2 rows at ty*2

    // staging index maps
    const int am = tid >> 3, akc = tid & 7;            // A: 1 float4 per thread
    const int bkk0 = tid >> 4, bnc = tid & 15;         // B: 2 float4 per thread (kk, kk+16)

    const int NC = K >> 5;            // K/32 chunks
    float acc[2][4] = {};

    // prefetch + write chunk 0
    {
        float4 aR = *(const float4*)&A[(bm + am) * K + akc * 4];
        float4 bR0 = *(const float4*)&W[(bkk0) * Nout + bn + bnc * 4];
        float4 bR1 = *(const float4*)&W[(bkk0 + 16) * Nout + bn + bnc * 4];
        *(float4*)&As[0][am][akc * 4] = aR;
        *(float4*)&Bs[0][bkk0][bnc * 4] = bR0;
        *(float4*)&Bs[0][bkk0 + 16][bnc * 4] = bR1;
    }
    __syncthreads();

    for (int c = 0; c < NC; ++c) {
        const int cur = c & 1;
        float4 aN, bN0, bN1;
        const bool more = (c + 1 < NC);
        if (more) {
            const int k0 = (c + 1) << 5;
            aN = *(const float4*)&A[(bm + am) * K + k0 + akc * 4];
            bN0 = *(const float4*)&W[(k0 + bkk0) * Nout + bn + bnc * 4];
            bN1 = *(const float4*)&W[(k0 + bkk0 + 16) * Nout + bn + bnc * 4];
        }
        // compute on buf cur
        #pragma unroll
        for (int kg = 0; kg < 8; ++kg) {
            float4 av0 = *(const float4*)&As[cur][ty * 2 + 0][kg * 4];
            float4 av1 = *(const float4*)&As[cur][ty * 2 + 1][kg * 4];
            #pragma unroll
            for (int q = 0; q < 4; ++q) {
                float4 bv = *(const float4*)&Bs[cur][kg * 4 + q][tx * 4];
                float a0 = (q == 0) ? av0.x : (q == 1) ? av0.y : (q == 2) ? av0.z : av0.w;
                float a1 = (q == 0) ? av1.x : (q == 1) ? av1.y : (q == 2) ? av1.z : av1.w;
                acc[0][0] = fmaf(a0, bv.x, acc[0][0]);
                acc[0][1] = fmaf(a0, bv.y, acc[0][1]);
                acc[0][2] = fmaf(a0, bv.z, acc[0][2]);
                acc[0][3] = fmaf(a0, bv.w, acc[0][3]);
                acc[1][0] = fmaf(a1, bv.x, acc[1][0]);
                acc[1][1] = fmaf(a1, bv.y, acc[1][1]);
                acc[1][2] = fmaf(a1, bv.z, acc[1][2]);
                acc[1][3] = fmaf(a1, bv.w, acc[1][3]);
            }
        }
        __syncthreads();
        if (more) {
            const int nxt = cur ^ 1;
            *(float4*)&As[nxt][am][akc * 4] = aN;
            *(float4*)&Bs[nxt][bkk0][bnc * 4] = bN0;
            *(float4*)&Bs[nxt][bkk0 + 16][bnc * 4] = bN1;
            __syncthreads();
        }
    }

    // epilogue: bias + act + store (float4)
    float4 bb = *(const float4*)&bias[bn + tx * 4];
    #pragma unroll
    for (int r = 0; r < 2; ++r) {
        float4 v;
        v.x = acc[r][0] + bb.x;
        v.y = acc[r][1] + bb.y;
        v.z = acc[r][2] + bb.z;
        v.w = acc[r][3] + bb.w;
        if (ACT == 1) {
            v.x = fmaxf(v.x, 0.f); v.y = fmaxf(v.y, 0.f);
            v.z = fmaxf(v.z, 0.f); v.w = fmaxf(v.w, 0.f);
        }
        *(float4*)&C[(bm + ty * 2 + r) * Nout + bn + tx * 4] = v;
    }
}

// ---------------- fused epilogue + loss reduction ----------------
__global__ __launch_bounds__(256) void loss_kernel(const float* __restrict__ mu_raw,
                                                   const float* __restrict__ lv_raw,
                                                   const float* __restrict__ ebsum,
                                                   const float* __restrict__ eb2sum,
                                                   float* __restrict__ acc) {
    const int wave = threadIdx.x >> 6;
    const int lane = threadIdx.x & 63;
    const int i = blockIdx.x * 4 + wave;
    const float invN = 1.0f / (float)N_ROWS;

    float m4[4], l4[4];
    float ss = 0.f;
    #pragma unroll
    for (int t = 0; t < 4; ++t) {
        int d = lane + t * 64;
        m4[t] = mu_raw[i * DIM + d];
        l4[t] = lv_raw[i * DIM + d];
        ss = fmaf(m4[t], m4[t], ss);
    }
    #pragma unroll
    for (int o = 32; o > 0; o >>= 1) ss += __shfl_xor(ss, o, 64);
    const float inv_norm = 1.f / fmaxf(sqrtf(ss), 1e-12f);

    float tsum = 0.f;
    #pragma unroll
    for (int t = 0; t < 4; ++t) {
        int d = lane + t * 64;
        float mu = m4[t] * inv_norm;
        float lv = tanhf(l4[t]);
        float iv = expf(-lv);
        float eb = ebsum[d] * invN;
        float eb2 = eb2sum[d] * invN;
        float diff2 = fmaf(mu, mu, fmaf(-2.f * mu, eb, eb2));
        tsum += fmaf(diff2, iv, lv);
    }
    #pragma unroll
    for (int o = 32; o > 0; o >>= 1) tsum += __shfl_xor(tsum, o, 64);
    if (lane == 0) atomicAdd(acc, tsum);
}

__global__ void finalize_kernel(const float* __restrict__ acc, float* __restrict__ out) {
    out[0] = acc[0] * (1.0f / (float)N_ROWS);
}

extern "C" void kernel_launch(void* const* d_in, const int* in_sizes, int n_in,
                              void* d_out, int out_size, void* d_ws, size_t ws_size,
                              hipStream_t stream) {
    const float* domain_a = (const float*)d_in[0];
    const float* domain_b = (const float*)d_in[1];
    const float* mu_w0 = (const float*)d_in[2];
    const float* mu_b0 = (const float*)d_in[3];
    const float* mu_w1 = (const float*)d_in[4];
    const float* mu_b1 = (const float*)d_in[5];
    const float* mu_w2 = (const float*)d_in[6];
    const float* mu_b2 = (const float*)d_in[7];
    const float* lv_w0 = (const float*)d_in[8];
    const float* lv_b0 = (const float*)d_in[9];
    const float* lv_w1 = (const float*)d_in[10];
    const float* lv_b1 = (const float*)d_in[11];
    const float* lv_w2 = (const float*)d_in[12];
    const float* lv_b2 = (const float*)d_in[13];

    float* ws = (float*)d_ws;
    float* ebsum  = ws + 0;        // 256
    float* eb2sum = ws + 256;      // 256
    float* acc    = ws + 512;      // 1
    float* h1_mu  = ws + 1024;
    float* h2_mu  = h1_mu + N_ROWS * HID;
    float* mu_raw = h2_mu + N_ROWS * HID;
    float* h1_lv  = mu_raw + N_ROWS * DIM;
    float* h2_lv  = h1_lv + N_ROWS * HID;
    float* lv_raw = h2_lv + N_ROWS * HID;

    zero_kernel<<<3, 256, 0, stream>>>(ws, 513);
    colstats_kernel<<<64, 256, 0, stream>>>(domain_b, ebsum, eb2sum);

    // stage 1: [1024x256] @ [256x512] -> h1 (relu), both nets
    gemm2<1><<<dim3(HID / 64, N_ROWS / 32, 2), 256, 0, stream>>>(
        domain_a, domain_a, mu_w0, lv_w0, mu_b0, lv_b0, h1_mu, h1_lv, N_ROWS, DIM, HID);
    // stage 2: [1024x512] @ [512x512] -> h2 (relu)
    gemm2<1><<<dim3(HID / 64, N_ROWS / 32, 2), 256, 0, stream>>>(
        h1_mu, h1_lv, mu_w1, lv_w1, mu_b1, lv_b1, h2_mu, h2_lv, N_ROWS, HID, HID);
    // stage 3: [1024x512] @ [512x256] -> raw (no act)
    gemm2<0><<<dim3(DIM / 64, N_ROWS / 32, 2), 256, 0, stream>>>(
        h2_mu, h2_lv, mu_w2, lv_w2, mu_b2, lv_b2, mu_raw, lv_raw, N_ROWS, HID, DIM);

    loss_kernel<<<N_ROWS / 4, 256, 0, stream>>>(mu_raw, lv_raw, ebsum, eb2sum, acc);
    finalize_kernel<<<1, 1, 0, stream>>>(acc, d_out ? (float*)d_out : nullptr);
}

// Round 3
// 52.980 us; speedup vs baseline: 4.4839x; 1.4593x over previous
//
#include <hip/hip_runtime.h>
#include <hip/hip_bf16.h>
#include <hip/hip_fp16.h>

#define N_ROWS 1024
#define DIM 256
#define HID 512

typedef _Float16 half_t;
typedef __attribute__((ext_vector_type(4))) _Float16 half4v;
typedef __attribute__((ext_vector_type(8))) _Float16 half8v;
typedef __attribute__((ext_vector_type(16))) float f32x16;

// ---------------- prep: zero stats, fp32->f16 convert, weight transpose ----------------
// grid (256, 8). y=0..5: weight transpose (tiled 32x32), y=6: domain_a copy, y=7: zero stats
__global__ __launch_bounds__(256) void prep_kernel(
    const float* __restrict__ a,
    const float* __restrict__ w0m, const float* __restrict__ w0l,
    const float* __restrict__ w1m, const float* __restrict__ w1l,
    const float* __restrict__ w2m, const float* __restrict__ w2l,
    half_t* __restrict__ a16,
    half_t* __restrict__ w0mt, half_t* __restrict__ w0lt,
    half_t* __restrict__ w1mt, half_t* __restrict__ w1lt,
    half_t* __restrict__ w2mt, half_t* __restrict__ w2lt,
    float* __restrict__ zreg) {
    __shared__ float T[32][33];
    const int y = blockIdx.y, bx = blockIdx.x, tid = threadIdx.x;

    if (y == 6) {                       // a copy: 256 blocks x 1024 els
        int base = bx * 1024 + tid * 4;
        float4 v = *(const float4*)&a[base];
        half4v h; h[0] = (half_t)v.x; h[1] = (half_t)v.y; h[2] = (half_t)v.z; h[3] = (half_t)v.w;
        *(half4v*)&a16[base] = h;
        return;
    }
    if (y == 7) {                       // zero ebsum/eb2sum/acc
        if (bx == 0) {
            for (int i = tid; i < 513; i += 256) zreg[i] = 0.f;
        }
        return;
    }
    const float* src; half_t* dst; int K, N, ltpr;
    switch (y) {
        case 0: src = w0m; dst = w0mt; K = DIM; N = HID; break;
        case 1: src = w0l; dst = w0lt; K = DIM; N = HID; break;
        case 2: src = w1m; dst = w1mt; K = HID; N = HID; break;
        case 3: src = w1l; dst = w1lt; K = HID; N = HID; break;
        case 4: src = w2m; dst = w2mt; K = HID; N = DIM; break;
        default: src = w2l; dst = w2lt; K = HID; N = DIM; break;
    }
    ltpr = (N == HID) ? 4 : 3;          // log2(N/32)
    const int ntiles = (K >> 5) << ltpr;
    if (bx >= ntiles) return;
    const int tk = bx >> ltpr, tn = bx & ((1 << ltpr) - 1);
    const int r = tid >> 3, c4 = (tid & 7) * 4;
    // coalesced read of W[k][n] tile
    float4 v = *(const float4*)&src[(tk * 32 + r) * N + tn * 32 + c4];
    T[r][c4] = v.x; T[r][c4 + 1] = v.y; T[r][c4 + 2] = v.z; T[r][c4 + 3] = v.w;
    __syncthreads();
    // coalesced write of Wt[n][k] tile
    half4v h;
    h[0] = (half_t)T[c4 + 0][r];
    h[1] = (half_t)T[c4 + 1][r];
    h[2] = (half_t)T[c4 + 2][r];
    h[3] = (half_t)T[c4 + 3][r];
    *(half4v*)&dst[(tn * 32 + r) * K + tk * 32 + c4] = h;
}

// ---------------- column stats of domain_b ----------------
__global__ __launch_bounds__(256) void colstats_kernel(const float* __restrict__ B,
                                                       float* __restrict__ ebsum,
                                                       float* __restrict__ eb2sum) {
    int d = threadIdx.x;
    int r0 = blockIdx.x * 16;
    float s = 0.f, s2 = 0.f;
    #pragma unroll
    for (int r = 0; r < 16; ++r) {
        float v = B[(r0 + r) * DIM + d];
        s += v; s2 += v * v;
    }
    atomicAdd(&ebsum[d], s);
    atomicAdd(&eb2sum[d], s2);
}

// ---------------- f16 MFMA GEMM: C = act(A @ W + bias) ----------------
// A: M x K f16 row-major. Wt: N x K f16 (pre-transposed). 64x64 tile, 4 waves,
// each wave one 32x32 fragment via v_mfma_f32_32x32x16_f16. K-step 32, dbuf.
template <int ACT, int OUT_F16>
__global__ __launch_bounds__(256) void gemm_mfma(
    const half_t* __restrict__ A0, const half_t* __restrict__ A1,
    const half_t* __restrict__ W0t, const half_t* __restrict__ W1t,
    const float* __restrict__ bias0, const float* __restrict__ bias1,
    void* __restrict__ C0, void* __restrict__ C1,
    int K, int Nout) {
    const int net = blockIdx.z;
    const half_t* __restrict__ A = net ? A1 : A0;
    const half_t* __restrict__ Wt = net ? W1t : W0t;
    const float* __restrict__ bias = net ? bias1 : bias0;
    void* __restrict__ Cp = net ? C1 : C0;

    __shared__ half_t As[2][64][40];   // stride 80B: uniform bank quads (5r+kb)%8
    __shared__ half_t Bs[2][64][40];

    const int tid = threadIdx.x;
    const int bm = blockIdx.y * 64, bn = blockIdx.x * 64;
    const int sr = tid >> 2;            // staging row 0..63
    const int sg = (tid & 3) * 8;       // staging k-offset (halves)

    const int wave = tid >> 6, lane = tid & 63;
    const int wr = (wave >> 1) * 32, wc = (wave & 1) * 32;
    const int lr = lane & 31, hi = lane >> 5;

    f32x16 acc;
    #pragma unroll
    for (int i = 0; i < 16; ++i) acc[i] = 0.f;

    const half_t* aP = &A[(bm + sr) * K + sg];
    const half_t* bP = &Wt[(bn + sr) * K + sg];
    const int NC = K >> 5;

    float4 aR = *(const float4*)aP;
    float4 bR = *(const float4*)bP;
    *(float4*)&As[0][sr][sg] = aR;
    *(float4*)&Bs[0][sr][sg] = bR;
    __syncthreads();

    for (int c = 0; c < NC; ++c) {
        const int cur = c & 1;
        const bool more = (c + 1 < NC);
        if (more) {
            aR = *(const float4*)(aP + (c + 1) * 32);
            bR = *(const float4*)(bP + (c + 1) * 32);
        }
        half8v av0 = *(const half8v*)&As[cur][wr + lr][hi * 8];
        half8v bv0 = *(const half8v*)&Bs[cur][wc + lr][hi * 8];
        acc = __builtin_amdgcn_mfma_f32_32x32x16_f16(av0, bv0, acc, 0, 0, 0);
        half8v av1 = *(const half8v*)&As[cur][wr + lr][hi * 8 + 16];
        half8v bv1 = *(const half8v*)&Bs[cur][wc + lr][hi * 8 + 16];
        acc = __builtin_amdgcn_mfma_f32_32x32x16_f16(av1, bv1, acc, 0, 0, 0);
        __syncthreads();
        if (more) {
            const int nxt = cur ^ 1;
            *(float4*)&As[nxt][sr][sg] = aR;
            *(float4*)&Bs[nxt][sr][sg] = bR;
            __syncthreads();
        }
    }

    // epilogue: C/D layout col=lane&31, row=(reg&3)+8*(reg>>2)+4*(lane>>5)
    const int col = bn + wc + lr;
    const float bv = bias[col];
    const int rbase = bm + wr + 4 * hi;
    #pragma unroll
    for (int r = 0; r < 16; ++r) {
        int row = rbase + (r & 3) + 8 * (r >> 2);
        float v = acc[r] + bv;
        if (ACT) v = fmaxf(v, 0.f);
        if (OUT_F16) ((half_t*)Cp)[row * Nout + col] = (half_t)v;
        else ((float*)Cp)[row * Nout + col] = v;
    }
}

// ---------------- fused epilogue + loss reduction ----------------
__global__ __launch_bounds__(256) void loss_kernel(const float* __restrict__ mu_raw,
                                                   const float* __restrict__ lv_raw,
                                                   const float* __restrict__ ebsum,
                                                   const float* __restrict__ eb2sum,
                                                   float* __restrict__ acc) {
    const int wave = threadIdx.x >> 6;
    const int lane = threadIdx.x & 63;
    const int i = blockIdx.x * 4 + wave;
    const float invN = 1.0f / (float)N_ROWS;

    float m4[4], l4[4];
    float ss = 0.f;
    #pragma unroll
    for (int t = 0; t < 4; ++t) {
        int d = lane + t * 64;
        m4[t] = mu_raw[i * DIM + d];
        l4[t] = lv_raw[i * DIM + d];
        ss = fmaf(m4[t], m4[t], ss);
    }
    #pragma unroll
    for (int o = 32; o > 0; o >>= 1) ss += __shfl_xor(ss, o, 64);
    const float inv_norm = 1.f / fmaxf(sqrtf(ss), 1e-12f);

    float tsum = 0.f;
    #pragma unroll
    for (int t = 0; t < 4; ++t) {
        int d = lane + t * 64;
        float mu = m4[t] * inv_norm;
        float lv = tanhf(l4[t]);
        float iv = expf(-lv);
        float eb = ebsum[d] * invN;
        float eb2 = eb2sum[d] * invN;
        float diff2 = fmaf(mu, mu, fmaf(-2.f * mu, eb, eb2));
        tsum += fmaf(diff2, iv, lv);
    }
    #pragma unroll
    for (int o = 32; o > 0; o >>= 1) tsum += __shfl_xor(tsum, o, 64);
    if (lane == 0) atomicAdd(acc, tsum);
}

__global__ void finalize_kernel(const float* __restrict__ acc, float* __restrict__ out) {
    out[0] = acc[0] * (1.0f / (float)N_ROWS);
}

extern "C" void kernel_launch(void* const* d_in, const int* in_sizes, int n_in,
                              void* d_out, int out_size, void* d_ws, size_t ws_size,
                              hipStream_t stream) {
    const float* domain_a = (const float*)d_in[0];
    const float* domain_b = (const float*)d_in[1];
    const float* mu_w0 = (const float*)d_in[2];
    const float* mu_b0 = (const float*)d_in[3];
    const float* mu_w1 = (const float*)d_in[4];
    const float* mu_b1 = (const float*)d_in[5];
    const float* mu_w2 = (const float*)d_in[6];
    const float* mu_b2 = (const float*)d_in[7];
    const float* lv_w0 = (const float*)d_in[8];
    const float* lv_b0 = (const float*)d_in[9];
    const float* lv_w1 = (const float*)d_in[10];
    const float* lv_b1 = (const float*)d_in[11];
    const float* lv_w2 = (const float*)d_in[12];
    const float* lv_b2 = (const float*)d_in[13];

    float* ws = (float*)d_ws;
    float* ebsum  = ws + 0;        // 256
    float* eb2sum = ws + 256;      // 256
    float* acc1   = ws + 512;      // 1 (pad to 1024)
    float* mu_raw = ws + 1024;                  // 1024*256 f32
    float* lv_raw = mu_raw + N_ROWS * DIM;      // 1024*256 f32

    half_t* hb    = (half_t*)(lv_raw + N_ROWS * DIM);
    half_t* a16   = hb;                         // 1024*256
    half_t* w0mt  = a16  + N_ROWS * DIM;        // 512*256
    half_t* w0lt  = w0mt + HID * DIM;
    half_t* w1mt  = w0lt + HID * DIM;           // 512*512
    half_t* w1lt  = w1mt + HID * HID;
    half_t* w2mt  = w1lt + HID * HID;           // 256*512
    half_t* w2lt  = w2mt + DIM * HID;
    half_t* h1m   = w2lt + DIM * HID;           // 1024*512
    half_t* h1l   = h1m  + N_ROWS * HID;
    half_t* h2m   = h1l  + N_ROWS * HID;
    half_t* h2l   = h2m  + N_ROWS * HID;

    prep_kernel<<<dim3(256, 8), 256, 0, stream>>>(
        domain_a, mu_w0, lv_w0, mu_w1, lv_w1, mu_w2, lv_w2,
        a16, w0mt, w0lt, w1mt, w1lt, w2mt, w2lt, ws);

    colstats_kernel<<<64, 256, 0, stream>>>(domain_b, ebsum, eb2sum);

    // stage 1: [1024x256] @ [256x512] -> h1 (relu)
    gemm_mfma<1, 1><<<dim3(HID / 64, N_ROWS / 64, 2), 256, 0, stream>>>(
        a16, a16, w0mt, w0lt, mu_b0, lv_b0, h1m, h1l, DIM, HID);
    // stage 2: [1024x512] @ [512x512] -> h2 (relu)
    gemm_mfma<1, 1><<<dim3(HID / 64, N_ROWS / 64, 2), 256, 0, stream>>>(
        h1m, h1l, w1mt, w1lt, mu_b1, lv_b1, h2m, h2l, HID, HID);
    // stage 3: [1024x512] @ [512x256] -> raw f32 (no act)
    gemm_mfma<0, 0><<<dim3(DIM / 64, N_ROWS / 64, 2), 256, 0, stream>>>(
        h2m, h2l, w2mt, w2lt, mu_b2, lv_b2, mu_raw, lv_raw, HID, DIM);

    loss_kernel<<<N_ROWS / 4, 256, 0, stream>>>(mu_raw, lv_raw, ebsum, eb2sum, acc1);
    finalize_kernel<<<1, 1, 0, stream>>>(acc1, (float*)d_out);
}